// Round 3
// baseline (238.827 us; speedup 1.0000x reference)
//
#include <hip/hip_runtime.h>

typedef unsigned short u16;
typedef unsigned int u32;
typedef __attribute__((ext_vector_type(8))) short s16x8;
typedef __attribute__((ext_vector_type(4))) float f32x4;

#define MFMA(a,b,c) __builtin_amdgcn_mfma_f32_16x16x32_bf16((a),(b),(c),0,0,0)
#define QSCALE 0.18033688011112042f   // 0.125 * log2(e): folds attn scale + exp->exp2

// raw barrier + compiler memory fence (NO implicit vmcnt(0) drain, unlike __syncthreads)
#define BAR() do { asm volatile("" ::: "memory"); __builtin_amdgcn_s_barrier(); asm volatile("" ::: "memory"); } while(0)
#define WAITV(n) asm volatile("s_waitcnt vmcnt(" #n ")" ::: "memory")

__device__ __forceinline__ u16 bfc(float f){
  union { float f; unsigned int u; } c; c.f = f;
  return (u16)((c.u + 0x7fffu + ((c.u >> 16) & 1u)) >> 16);
}
// pack 2 f32 -> 2 bf16 (round-half-up) in one v_perm_b32
__device__ __forceinline__ u32 pkbf(float lo, float hi){
  union { float f; u32 u; } a, b; a.f = lo; b.f = hi;
  return __builtin_amdgcn_perm(b.u + 0x8000u, a.u + 0x8000u, 0x07060302u);
}
__device__ __forceinline__ float fexp2(float x){ return __builtin_amdgcn_exp2f(x); }
__device__ __forceinline__ f32x4 zero4(){ f32x4 z; z[0]=0.f; z[1]=0.f; z[2]=0.f; z[3]=0.f; return z; }

__device__ __forceinline__ void gload_lds16(const u16* g, u16* l){
  __builtin_amdgcn_global_load_lds((const __attribute__((address_space(1))) unsigned int*)g,
                                   (__attribute__((address_space(3))) unsigned int*)l, 16, 0, 0);
}

// ---------------- x fp32 -> bf16
__global__ __launch_bounds__(256) void k_cvt(const float* __restrict__ x, u16* __restrict__ xb){
  int i = (blockIdx.x * 256 + threadIdx.x) * 4;
  float4 v = *(const float4*)(x + i);
  *(uint2*)(xb + i) = make_uint2(pkbf(v.x, v.y), pkbf(v.z, v.w));
}

// ---------------- fused weight transpose+convert (Wq|Wk|Wv|Wo): [m][1024][64] f32 -> [m][64][1024] bf16
__global__ __launch_bounds__(256) void k_twp(const float* __restrict__ Wq, const float* __restrict__ Wk,
    const float* __restrict__ Wv, const float* __restrict__ Wo,
    u16* __restrict__ wt, u16* __restrict__ wot){
  __shared__ float t[64][65];
  int y = blockIdx.y, k0 = blockIdx.x * 64, tid = threadIdx.x;
  const float* src; u16* dst;
  if (y < 16)      { src = Wq + (size_t)y * 65536;        dst = wt + (size_t)y * 65536; }
  else if (y < 32) { src = Wk + (size_t)(y-16) * 65536;   dst = wt + (size_t)y * 65536; }
  else if (y < 48) { src = Wv + (size_t)(y-32) * 65536;   dst = wt + (size_t)y * 65536; }
  else             { src = Wo;                            dst = wot; }
  const float* s = src + (size_t)k0 * 64;
  int kl = tid >> 2, nc = (tid & 3) * 16;
  #pragma unroll
  for (int j = 0; j < 4; j++){
    float4 v = *(const float4*)(s + kl * 64 + nc + j * 4);
    t[kl][nc + j*4 + 0] = v.x; t[kl][nc + j*4 + 1] = v.y;
    t[kl][nc + j*4 + 2] = v.z; t[kl][nc + j*4 + 3] = v.w;
  }
  __syncthreads();
  int n = tid >> 2, kc = (tid & 3) * 16;
  u16 o[16];
  #pragma unroll
  for (int j = 0; j < 16; j++) o[j] = bfc(t[kc + j][n]);
  u16* d = dst + (size_t)n * 1024 + k0 + kc;
  *(uint4*)(d)     = *(uint4*)&o[0];
  *(uint4*)(d + 8) = *(uint4*)&o[8];
}

// ---------------- fused QKV projection (r3): GEMM M=8192, N=3072, K=1024.
// 256x256 tile, 8 waves (2Mx4N, each wave 128x64 out), K-sliced ring pipeline:
// LDS = 4-slot ring, slot = one K=32 slice of A[256]+B[256] (32KB). Per phase:
//   s_waitcnt vmcnt(8)  (slices s+1,s+2 stay in flight -- NEVER drained to 0)
//   s_barrier           (slot (s-1)&3 freed; slice s guaranteed landed chip-wide)
//   stage slice s+3 into the freed slot (4x global_load_lds per wave)
//   12x ds_read_b128 -> 32 MFMA (setprio-wrapped)
// Race-free ledger: slot written at phase s was last ds_read at phase s-1; those
// reads complete before their wave passes phase-s's barrier; gload issue is
// post-barrier. LDS layout: 2 M-rows packed per 128B LDS row, 8-chunk XOR
// swizzle (phys = chunk ^ (row&7)) -- same conflict-free pattern as before,
// staged via pre-swizzled per-lane global source addresses.
__global__ __launch_bounds__(512, 2) void k_qkv(const u16* __restrict__ xb, const u16* __restrict__ wt,
    const float* __restrict__ bq, const float* __restrict__ bk, const float* __restrict__ bv,
    u16* __restrict__ Qo, u16* __restrict__ Ko, u16* __restrict__ VT){
  __shared__ u16 lds[65536];            // 128 KiB: A ring 4x16KB | B ring 4x16KB
  u16* Ab = lds;
  u16* Bb = lds + 32768;
  int tid = threadIdx.x, w = tid >> 6, lane = tid & 63;
  int l16 = lane & 15, g = lane >> 4;
  int wm = w >> 2, wn = w & 3;          // wave -> 128-row half x 64-col quarter
  int row0 = blockIdx.x * 256, col0 = blockIdx.y * 256;
  f32x4 acc[8][4];
  #pragma unroll
  for (int mt = 0; mt < 8; mt++)
    #pragma unroll
    for (int nt = 0; nt < 4; nt++) acc[mt][nt] = zero4();

  // ---- staging setup: waves 0-3 stage A (4 x 1KB segments each), 4-7 stage B
  bool isB = (w >= 4);
  int wseg = (w & 3) * 4;
  const u16* gsrc = isB ? wt : xb;
  int gbase0 = isB ? col0 : row0;
  const u16* gp[4];
  #pragma unroll
  for (int j = 0; j < 4; j++){
    int sg = wseg + j;
    int r = sg * 8 + (lane >> 3);       // LDS row this lane fills
    int pc = lane & 7;                  // physical 16B chunk
    int lc = pc ^ (r & 7);              // logical chunk (inverse swizzle)
    int m = 2 * r + (lc >> 2);          // global row (2 rows packed per LDS row)
    int kk = (lc & 3) * 8;              // k-offset within 32-slice
    gp[j] = gsrc + (size_t)(gbase0 + m) * 1024 + kk;
  }
  u16* lring = isB ? Bb : Ab;

  auto stage = [&](int s3){
    u16* lslot = lring + (s3 & 3) * 8192;
    int ko = s3 * 32;
    #pragma unroll
    for (int j = 0; j < 4; j++)
      gload_lds16(gp[j] + ko, lslot + (wseg + j) * 512);
  };

  auto phase = [&](int s){
    const u16* Asl = Ab + (s & 3) * 8192;
    const u16* Bsl = Bb + (s & 3) * 8192;
    s16x8 af[8], bf[4];
    #pragma unroll
    for (int nt = 0; nt < 4; nt++){
      int nr = wn * 64 + nt * 16 + l16;
      int r = nr >> 1, pc = (((nr & 1) << 2) | g) ^ (r & 7);
      bf[nt] = *(const s16x8*)&Bsl[r * 64 + pc * 8];
    }
    #pragma unroll
    for (int mt = 0; mt < 8; mt++){
      int mr = wm * 128 + mt * 16 + l16;
      int r = mr >> 1, pc = (((mr & 1) << 2) | g) ^ (r & 7);
      af[mt] = *(const s16x8*)&Asl[r * 64 + pc * 8];
    }
    __builtin_amdgcn_s_setprio(1);
    #pragma unroll
    for (int mt = 0; mt < 8; mt++)
      #pragma unroll
      for (int nt = 0; nt < 4; nt++)
        acc[mt][nt] = MFMA(af[mt], bf[nt], acc[mt][nt]);
    __builtin_amdgcn_s_setprio(0);
  };

  // ---- prologue: 3 slices in flight
  stage(0); stage(1); stage(2);
  // ---- main: 29 phases with stage; vmcnt(8) leaves 2 slices (8 loads) in flight
  for (int s = 0; s < 29; ++s){
    WAITV(8);
    BAR();
    stage(s + 3);
    phase(s);
  }
  // ---- tail: drain ring
  WAITV(8); BAR(); phase(29);
  WAITV(4); BAR(); phase(30);
  WAITV(0); BAR(); phase(31);

  // ---- epilogue (same math as r2, extended to 8x4 frags; wi block-uniform)
  #pragma unroll
  for (int nt = 0; nt < 4; nt++){
    int n = col0 + wn * 64 + nt * 16 + l16;
    int wi = n >> 10, hh = (n >> 6) & 15, dh = n & 63;
    const float* bptr = (wi == 0) ? bq : (wi == 1) ? bk : bv;
    float bval = bptr[hh * 64 + dh];
    #pragma unroll
    for (int mt = 0; mt < 8; mt++){
      int m0 = row0 + wm * 128 + mt * 16 + g * 4;
      int bb = m0 >> 11, ss = m0 & 2047;
      if (wi == 2){
        u32 p0 = pkbf(acc[mt][nt][0] + bval, acc[mt][nt][1] + bval);
        u32 p1 = pkbf(acc[mt][nt][2] + bval, acc[mt][nt][3] + bval);
        *(uint2*)&VT[(((size_t)bb * 16 + hh) * 64 + dh) * 2048 + ss] = make_uint2(p0, p1);
      } else {
        u16* dst = (wi == 0) ? Qo : Ko;
        float scl = (wi == 0) ? QSCALE : 1.0f;
        #pragma unroll
        for (int i = 0; i < 4; i++)
          dst[(((size_t)bb * 16 + hh) * 2048 + ss + i) * 64 + dh] = bfc((acc[mt][nt][i] + bval) * scl);
      }
    }
  }
}

// ---------------- flash attention, S^T + FIXED-MAX softmax.
// wave = 32 q-rows x FULL k-range; 3 blocks/CU under launch_bounds(256,3), no spill.
__global__ __launch_bounds__(256, 3) void k_attn(const u16* __restrict__ Q, const u16* __restrict__ Kg,
    const u16* __restrict__ VT, u16* __restrict__ O){
  __shared__ u16 smem[18432];           // 36864B: Ks[64][72] | Vt[64][72] | Ps[4][32][72]
  u16* Ks = smem;                       // [kpos][dh], stride 72
  u16* Vt = smem + 4608;                // [dh][kpos], stride 72
  u16* Ps = smem + 9216;                // per-wave [32 q][72] (64 k + pad)
  int hbi = blockIdx.x;
  int qt = 15 - (int)blockIdx.y;        // long blocks (qt=15, 32 kt-iters) first
  int b = hbi >> 4, h = hbi & 15;
  int tid = threadIdx.x, wave = tid >> 6, lane = tid & 63;
  int l16 = lane & 15, g = lane >> 4;
  size_t hb = (size_t)hbi * 2048 * 64;
  const u16* kbase = Kg + hb;
  const u16* vbase = VT + hb;           // [64][2048]
  int sr = tid >> 3, scc = (tid & 7) * 8;
  u16* PsW = Ps + wave * (32 * 72);
  int q0 = qt * 128 + wave * 32;        // wave's 32 q-rows
  s16x8 bq[2][2];
  #pragma unroll
  for (int j = 0; j < 2; j++)
    #pragma unroll
    for (int c = 0; c < 2; c++)
      bq[j][c] = *(const s16x8*)(Q + hb + (size_t)(q0 + j*16 + l16) * 64 + c*32 + g*8);
  f32x4 accO[4][2];                     // [mt(dh)][j(q)]
  #pragma unroll
  for (int mt = 0; mt < 4; mt++)
    #pragma unroll
    for (int j = 0; j < 2; j++) accO[mt][j] = zero4();
  float rs0 = 0.f, rs1 = 0.f;           // per-lane partial row sums (j=0,1)
  int nkt = 2 * qt + 2;
  uint4 ka0, ka1, va0, va1;
  ka0 = *(const uint4*)(kbase + (size_t)(sr)      * 64 + scc);
  ka1 = *(const uint4*)(kbase + (size_t)(sr + 32) * 64 + scc);
  va0 = *(const uint4*)(vbase + (size_t)(sr)      * 2048 + scc);
  va1 = *(const uint4*)(vbase + (size_t)(sr + 32) * 2048 + scc);
  *(uint4*)&Ks[sr * 72 + scc] = ka0; *(uint4*)&Ks[(sr + 32) * 72 + scc] = ka1;
  *(uint4*)&Vt[sr * 72 + scc] = va0; *(uint4*)&Vt[(sr + 32) * 72 + scc] = va1;
  __syncthreads();
  for (int kt = 0; kt < nkt; kt++){
    if (kt + 1 < nkt){                  // register-prefetch next K/V tile (T14: issue early)
      int kb2 = (kt + 1) * 64;
      ka0 = *(const uint4*)(kbase + (size_t)(kb2 + sr)      * 64 + scc);
      ka1 = *(const uint4*)(kbase + (size_t)(kb2 + sr + 32) * 64 + scc);
      va0 = *(const uint4*)(vbase + (size_t)(sr)      * 2048 + kb2 + scc);
      va1 = *(const uint4*)(vbase + (size_t)(sr + 32) * 2048 + kb2 + scc);
    }
    int ks0 = kt * 64;                  // tile's absolute k start
    if (ks0 <= q0 + 31){                // wave-uniform activity
      // ---- QK^T: S^T[64k][32q], per 16-k block
      #pragma unroll
      for (int kb = 0; kb < 4; kb++){
        s16x8 ak0 = *(const s16x8*)&Ks[(kb*16 + l16) * 72 + g*8];
        s16x8 ak1 = *(const s16x8*)&Ks[(kb*16 + l16) * 72 + 32 + g*8];
        #pragma unroll
        for (int j = 0; j < 2; j++){
          f32x4 s = zero4();
          s = MFMA(ak0, bq[j][0], s);
          s = MFMA(ak1, bq[j][1], s);
          if (ks0 + kb*16 + 15 > q0 + j*16){  // diagonal straddle: causal mask
            int qrow = q0 + j*16 + l16;
            #pragma unroll
            for (int r = 0; r < 4; r++)
              if (ks0 + kb*16 + g*4 + r > qrow) s[r] = -1e30f;
          }
          float p0 = fexp2(s[0]), p1 = fexp2(s[1]), p2 = fexp2(s[2]), p3 = fexp2(s[3]);
          if (j == 0) rs0 += (p0 + p1) + (p2 + p3);
          else        rs1 += (p0 + p1) + (p2 + p3);
          *(uint2*)&PsW[(j*16 + l16) * 72 + kb*16 + g*4] = make_uint2(pkbf(p0, p1), pkbf(p2, p3));
        }
      }
      // ---- PV: O^T[dh][q] += V^T[dh][k] * P^T[k][q], k = 64
      s16x8 av[4][2];
      #pragma unroll
      for (int mt = 0; mt < 4; mt++)
        #pragma unroll
        for (int kc = 0; kc < 2; kc++)
          av[mt][kc] = *(const s16x8*)&Vt[(mt*16 + l16) * 72 + kc*32 + g*8];
      #pragma unroll
      for (int j = 0; j < 2; j++){
        s16x8 bp0 = *(const s16x8*)&PsW[(j*16 + l16) * 72 + g*8];
        s16x8 bp1 = *(const s16x8*)&PsW[(j*16 + l16) * 72 + 32 + g*8];
        #pragma unroll
        for (int mt = 0; mt < 4; mt++){
          accO[mt][j] = MFMA(av[mt][0], bp0, accO[mt][j]);
          accO[mt][j] = MFMA(av[mt][1], bp1, accO[mt][j]);
        }
      }
    }
    if (kt + 1 < nkt){
      __syncthreads();
      *(uint4*)&Ks[sr * 72 + scc] = ka0; *(uint4*)&Ks[(sr + 32) * 72 + scc] = ka1;
      *(uint4*)&Vt[sr * 72 + scc] = va0; *(uint4*)&Vt[(sr + 32) * 72 + scc] = va1;
      __syncthreads();
    }
  }
  // per-wave normalize + store (no cross-wave merge needed)
  float rinv[2];
  #pragma unroll
  for (int j = 0; j < 2; j++){
    float l = (j == 0) ? rs0 : rs1;
    l += __shfl_xor(l, 16);
    l += __shfl_xor(l, 32);
    rinv[j] = 1.0f / l;
  }
  #pragma unroll
  for (int mt = 0; mt < 4; mt++)
    #pragma unroll
    for (int j = 0; j < 2; j++){
      float o0 = accO[mt][j][0] * rinv[j];
      float o1 = accO[mt][j][1] * rinv[j];
      float o2 = accO[mt][j][2] * rinv[j];
      float o3 = accO[mt][j][3] * rinv[j];
      *(uint2*)&O[((size_t)b * 2048 + q0 + j*16 + l16) * 1024 + h*64 + mt*16 + g*4] =
          make_uint2(pkbf(o0, o1), pkbf(o2, o3));
    }
}

// ---------------- output projection with split-K=4: [8192,1024] @ Wo^T + bo -> fp32 (atomicAdd)
__global__ __launch_bounds__(256) void k_oproj(const u16* __restrict__ Ob, const u16* __restrict__ wot,
    const float* __restrict__ bo, float* __restrict__ out){
  __shared__ u16 As[64][72];
  __shared__ u16 Bs[64][72];
  int rb = blockIdx.x, kc = blockIdx.y;
  int tid = threadIdx.x, wave = tid >> 6, lane = tid & 63;
  int l16 = lane & 15, g = lane >> 4;
  int wr = (wave & 1) * 32, wc = (wave >> 1) * 32;
  int row0 = rb * 64;
  f32x4 acc[2][2];
  acc[0][0]=zero4(); acc[0][1]=zero4(); acc[1][0]=zero4(); acc[1][1]=zero4();
  int r0s = tid >> 3, cc0 = (tid & 7) * 8, r1s = r0s + 32;
  for (int k0 = kc * 256; k0 < kc * 256 + 256; k0 += 64){
    __syncthreads();
    *(uint4*)&As[r0s][cc0] = *(const uint4*)(Ob + (size_t)(row0 + r0s) * 1024 + k0 + cc0);
    *(uint4*)&As[r1s][cc0] = *(const uint4*)(Ob + (size_t)(row0 + r1s) * 1024 + k0 + cc0);
    *(uint4*)&Bs[r0s][cc0] = *(const uint4*)(wot + (size_t)r0s * 1024 + k0 + cc0);
    *(uint4*)&Bs[r1s][cc0] = *(const uint4*)(wot + (size_t)r1s * 1024 + k0 + cc0);
    __syncthreads();
    #pragma unroll
    for (int c = 0; c < 2; c++){
      int kcc = c * 32;
      s16x8 a0 = *(const s16x8*)&As[wr      + l16][kcc + g * 8];
      s16x8 a1 = *(const s16x8*)&As[wr + 16 + l16][kcc + g * 8];
      s16x8 b0 = *(const s16x8*)&Bs[wc      + l16][kcc + g * 8];
      s16x8 b1 = *(const s16x8*)&Bs[wc + 16 + l16][kcc + g * 8];
      acc[0][0] = MFMA(a0, b0, acc[0][0]);
      acc[0][1] = MFMA(a0, b1, acc[0][1]);
      acc[1][0] = MFMA(a1, b0, acc[1][0]);
      acc[1][1] = MFMA(a1, b1, acc[1][1]);
    }
  }
  #pragma unroll
  for (int rt = 0; rt < 2; rt++){
    #pragma unroll
    for (int ct = 0; ct < 2; ct++){
      int col = wc + ct * 16 + l16;
      float bval = (kc == 0) ? bo[col] : 0.f;
      #pragma unroll
      for (int i = 0; i < 4; i++){
        int row = row0 + wr + rt * 16 + g * 4 + i;
        atomicAdd(&out[(size_t)row * 64 + col], acc[rt][ct][i] + bval);
      }
    }
  }
}

extern "C" void kernel_launch(void* const* d_in, const int* in_sizes, int n_in,
                              void* d_out, int out_size, void* d_ws, size_t ws_size,
                              hipStream_t stream){
  const float* x  = (const float*)d_in[0];
  const float* Wq = (const float*)d_in[1];
  const float* bq = (const float*)d_in[2];
  const float* Wk = (const float*)d_in[3];
  const float* bk = (const float*)d_in[4];
  const float* Wv = (const float*)d_in[5];
  const float* bv = (const float*)d_in[6];
  const float* Wo = (const float*)d_in[7];
  const float* bo = (const float*)d_in[8];

  u16* xb  = (u16*)d_ws;          // [8192][1024] bf16 x ; reused as attention output Ob
  u16* wt  = xb  + 8388608;       // [3][16][64][1024] transposed qkv weights
  u16* wot = wt  + 3145728;       // [64][1024] transposed Wo
  u16* Qb  = wot + 65536;         // [B][H][S][64] (pre-scaled by QSCALE)
  u16* Kb  = Qb  + 8388608;       // [B][H][S][64]
  u16* VTb = Kb  + 8388608;       // [B][H][64][S]
  u16* Ob  = xb;                  // alias: x dead after k_qkv
  float* out = (float*)d_out;

  hipMemsetAsync(d_out, 0, (size_t)out_size * sizeof(float), stream);
  k_cvt<<<8192, 256, 0, stream>>>(x, xb);
  k_twp<<<dim3(16, 49), 256, 0, stream>>>(Wq, Wk, Wv, Wo, wt, wot);
  k_qkv<<<dim3(32, 12), 512, 0, stream>>>(xb, wt, bq, bk, bv, Qb, Kb, VTb);
  k_attn<<<dim3(64, 16), 256, 0, stream>>>(Qb, Kb, VTb, Ob);
  k_oproj<<<dim3(128, 4), 256, 0, stream>>>(Ob, wot, bo, out);
}

// Round 4
// 232.170 us; speedup vs baseline: 1.0287x; 1.0287x over previous
//
#include <hip/hip_runtime.h>

typedef unsigned short u16;
typedef unsigned int u32;
typedef __attribute__((ext_vector_type(8))) short s16x8;
typedef __attribute__((ext_vector_type(4))) float f32x4;

#define MFMA(a,b,c) __builtin_amdgcn_mfma_f32_16x16x32_bf16((a),(b),(c),0,0,0)
#define QSCALE 0.18033688011112042f   // 0.125 * log2(e): folds attn scale + exp->exp2

// raw barrier + compiler memory fence (NO implicit vmcnt(0) drain, unlike __syncthreads)
#define BAR() do { asm volatile("" ::: "memory"); __builtin_amdgcn_s_barrier(); asm volatile("" ::: "memory"); } while(0)
#define WAITV0() asm volatile("s_waitcnt vmcnt(0)" ::: "memory")

__device__ __forceinline__ u16 bfc(float f){
  union { float f; unsigned int u; } c; c.f = f;
  return (u16)((c.u + 0x7fffu + ((c.u >> 16) & 1u)) >> 16);
}
// pack 2 f32 -> 2 bf16 (round-half-up) in one v_perm_b32
__device__ __forceinline__ u32 pkbf(float lo, float hi){
  union { float f; u32 u; } a, b; a.f = lo; b.f = hi;
  return __builtin_amdgcn_perm(b.u + 0x8000u, a.u + 0x8000u, 0x07060302u);
}
__device__ __forceinline__ float fexp2(float x){ return __builtin_amdgcn_exp2f(x); }
__device__ __forceinline__ f32x4 zero4(){ f32x4 z; z[0]=0.f; z[1]=0.f; z[2]=0.f; z[3]=0.f; return z; }

__device__ __forceinline__ void gload_lds16(const u16* g, u16* l){
  __builtin_amdgcn_global_load_lds((const __attribute__((address_space(1))) unsigned int*)g,
                                   (__attribute__((address_space(3))) unsigned int*)l, 16, 0, 0);
}

// ---------------- x fp32 -> bf16
__global__ __launch_bounds__(256) void k_cvt(const float* __restrict__ x, u16* __restrict__ xb){
  int i = (blockIdx.x * 256 + threadIdx.x) * 4;
  float4 v = *(const float4*)(x + i);
  *(uint2*)(xb + i) = make_uint2(pkbf(v.x, v.y), pkbf(v.z, v.w));
}

// ---------------- fused weight transpose+convert (Wq|Wk|Wv|Wo): [m][1024][64] f32 -> [m][64][1024] bf16
__global__ __launch_bounds__(256) void k_twp(const float* __restrict__ Wq, const float* __restrict__ Wk,
    const float* __restrict__ Wv, const float* __restrict__ Wo,
    u16* __restrict__ wt, u16* __restrict__ wot){
  __shared__ float t[64][65];
  int y = blockIdx.y, k0 = blockIdx.x * 64, tid = threadIdx.x;
  const float* src; u16* dst;
  if (y < 16)      { src = Wq + (size_t)y * 65536;        dst = wt + (size_t)y * 65536; }
  else if (y < 32) { src = Wk + (size_t)(y-16) * 65536;   dst = wt + (size_t)y * 65536; }
  else if (y < 48) { src = Wv + (size_t)(y-32) * 65536;   dst = wt + (size_t)y * 65536; }
  else             { src = Wo;                            dst = wot; }
  const float* s = src + (size_t)k0 * 64;
  int kl = tid >> 2, nc = (tid & 3) * 16;
  #pragma unroll
  for (int j = 0; j < 4; j++){
    float4 v = *(const float4*)(s + kl * 64 + nc + j * 4);
    t[kl][nc + j*4 + 0] = v.x; t[kl][nc + j*4 + 1] = v.y;
    t[kl][nc + j*4 + 2] = v.z; t[kl][nc + j*4 + 3] = v.w;
  }
  __syncthreads();
  int n = tid >> 2, kc = (tid & 3) * 16;
  u16 o[16];
  #pragma unroll
  for (int j = 0; j < 16; j++) o[j] = bfc(t[kc + j][n]);
  u16* d = dst + (size_t)n * 1024 + k0 + kc;
  *(uint4*)(d)     = *(uint4*)&o[0];
  *(uint4*)(d + 8) = *(uint4*)&o[8];
}

// ---------------- fused QKV projection (r4): GEMM M=8192, N=3072, K=1024; 128x128 tile.
// r2's proven geometry (4 waves, 3 blocks/CU TLP, 32KB LDS) + 1-deep pipeline at
// ZERO LDS cost: BK 64->32, double-buffered (4 slots x 8KB = same 32KB).
// Per K-step (T3-minimum): { STAGE(t+1, slot^1); ds_read(t); 16 MFMA; vmcnt(0); bar }
// -> stage latency hides under compute (r2 exposed it via stage->drain->compute).
// Race ledger: slot (t+1)&1 last read in iter t-1, reads complete before t-1's end
// barrier (WAR-safe); RAW via per-wave vmcnt(0) + barrier. Swizzle for 64B rows:
// phys_chunk = g ^ ((row>>1)&3): 16 lanes -> 8 (parity,chunk) slots x2 = 2-way (free).
// Stage source is pre-swizzled with the same involution; ds_read offsets precomputed.
__global__ __launch_bounds__(256) void k_qkv(const u16* __restrict__ xb, const u16* __restrict__ wt,
    const float* __restrict__ bq, const float* __restrict__ bk, const float* __restrict__ bv,
    u16* __restrict__ Qo, u16* __restrict__ Ko, u16* __restrict__ VT){
  __shared__ u16 lds[16384];            // 32 KB: A0[4096] A1[4096] B0[4096] B1[4096] (u16 units)
  int tid = threadIdx.x, w = tid >> 6, lane = tid & 63;
  int l16 = lane & 15, g = lane >> 4;
  int row0 = blockIdx.x * 128, col0 = blockIdx.y * 128;
  int wm = (w & 1) * 64, wn = (w >> 1) * 64;
  f32x4 acc[4][4];
  #pragma unroll
  for (int mt = 0; mt < 4; mt++)
    #pragma unroll
    for (int nt = 0; nt < 4; nt++) acc[mt][nt] = zero4();

  // stage sources: thread t fills phys 16B chunk t of each 8KB half-slot.
  // phys (row = gi*64 + t>>2, pc = t&3) holds logical chunk lc = pc ^ ((row>>1)&3);
  // (row>>1)&3 == (t>>3)&3 for both gi (64 == 0 mod 8 rows).
  int trow = tid >> 2;
  int lc = (tid & 3) ^ ((tid >> 3) & 3);
  const u16* gpa = xb + (size_t)(row0 + trow) * 1024 + lc * 8;
  const u16* gpb = wt + (size_t)(col0 + trow) * 1024 + lc * 8;
  // per-wave LDS dest bases (gload_lds adds lane*16B): half-slot gi at gi*2048 u16
  u16* lA0 = &lds[w * 512];
  u16* lA1 = &lds[2048 + w * 512];
  u16* lB0 = &lds[8192 + w * 512];
  u16* lB1 = &lds[8192 + 2048 + w * 512];

  // loop-invariant swizzled ds_read offsets (u16 units; row stride 32)
  int afo[4], bfo[4];
  #pragma unroll
  for (int mt = 0; mt < 4; mt++){
    int r = wm + mt * 16 + l16;
    afo[mt] = r * 32 + ((g ^ ((r >> 1) & 3)) * 8);
  }
  #pragma unroll
  for (int nt = 0; nt < 4; nt++){
    int r = wn + nt * 16 + l16;
    bfo[nt] = 8192 + r * 32 + ((g ^ ((r >> 1) & 3)) * 8);
  }

  // prologue: stage slice 0 into slot 0, drain, barrier
  gload_lds16(gpa,              lA0);
  gload_lds16(gpa + 64 * 1024,  lA1);
  gload_lds16(gpb,              lB0);
  gload_lds16(gpb + 64 * 1024,  lB1);
  WAITV0(); BAR();

  #pragma unroll 2
  for (int s = 0; s < 32; ++s){
    if (s < 31){                        // stage slice s+1 into slot (s+1)&1
      int ko = (s + 1) * 32;
      int dsel = ((s + 1) & 1) * 4096;
      gload_lds16(gpa + ko,             lA0 + dsel);
      gload_lds16(gpa + ko + 64 * 1024, lA1 + dsel);
      gload_lds16(gpb + ko,             lB0 + dsel);
      gload_lds16(gpb + ko + 64 * 1024, lB1 + dsel);
    }
    int sel = (s & 1) * 4096;
    s16x8 af[4], bf[4];
    #pragma unroll
    for (int mt = 0; mt < 4; mt++) af[mt] = *(const s16x8*)&lds[sel + afo[mt]];
    #pragma unroll
    for (int nt = 0; nt < 4; nt++) bf[nt] = *(const s16x8*)&lds[sel + bfo[nt]];
    __builtin_amdgcn_s_setprio(1);
    #pragma unroll
    for (int mt = 0; mt < 4; mt++)
      #pragma unroll
      for (int nt = 0; nt < 4; nt++) acc[mt][nt] = MFMA(af[mt], bf[nt], acc[mt][nt]);
    __builtin_amdgcn_s_setprio(0);
    WAITV0(); BAR();
  }

  // ---- epilogue (identical math to r2)
  #pragma unroll
  for (int nt = 0; nt < 4; nt++){
    int n = col0 + wn + nt * 16 + l16;
    int wi = n >> 10, hh = (n >> 6) & 15, dh = n & 63;
    const float* bptr = (wi == 0) ? bq : (wi == 1) ? bk : bv;
    float bval = bptr[hh * 64 + dh];
    #pragma unroll
    for (int mt = 0; mt < 4; mt++){
      int m0 = row0 + wm + mt * 16 + g * 4;
      int bb = m0 >> 11, ss = m0 & 2047;
      if (wi == 2){
        u32 p0 = pkbf(acc[mt][nt][0] + bval, acc[mt][nt][1] + bval);
        u32 p1 = pkbf(acc[mt][nt][2] + bval, acc[mt][nt][3] + bval);
        *(uint2*)&VT[(((size_t)bb * 16 + hh) * 64 + dh) * 2048 + ss] = make_uint2(p0, p1);
      } else {
        u16* dst = (wi == 0) ? Qo : Ko;
        float scl = (wi == 0) ? QSCALE : 1.0f;
        #pragma unroll
        for (int i = 0; i < 4; i++)
          dst[(((size_t)bb * 16 + hh) * 2048 + ss + i) * 64 + dh] = bfc((acc[mt][nt][i] + bval) * scl);
      }
    }
  }
}

// ---------------- flash attention, S^T + FIXED-MAX softmax.
// wave = 32 q-rows x FULL k-range; 3 blocks/CU under launch_bounds(256,3), no spill.
__global__ __launch_bounds__(256, 3) void k_attn(const u16* __restrict__ Q, const u16* __restrict__ Kg,
    const u16* __restrict__ VT, u16* __restrict__ O){
  __shared__ u16 smem[18432];           // 36864B: Ks[64][72] | Vt[64][72] | Ps[4][32][72]
  u16* Ks = smem;                       // [kpos][dh], stride 72
  u16* Vt = smem + 4608;                // [dh][kpos], stride 72
  u16* Ps = smem + 9216;                // per-wave [32 q][72] (64 k + pad)
  int hbi = blockIdx.x;
  int qt = 15 - (int)blockIdx.y;        // long blocks (qt=15, 32 kt-iters) first
  int b = hbi >> 4, h = hbi & 15;
  int tid = threadIdx.x, wave = tid >> 6, lane = tid & 63;
  int l16 = lane & 15, g = lane >> 4;
  size_t hb = (size_t)hbi * 2048 * 64;
  const u16* kbase = Kg + hb;
  const u16* vbase = VT + hb;           // [64][2048]
  int sr = tid >> 3, scc = (tid & 7) * 8;
  u16* PsW = Ps + wave * (32 * 72);
  int q0 = qt * 128 + wave * 32;        // wave's 32 q-rows
  s16x8 bq[2][2];
  #pragma unroll
  for (int j = 0; j < 2; j++)
    #pragma unroll
    for (int c = 0; c < 2; c++)
      bq[j][c] = *(const s16x8*)(Q + hb + (size_t)(q0 + j*16 + l16) * 64 + c*32 + g*8);
  f32x4 accO[4][2];                     // [mt(dh)][j(q)]
  #pragma unroll
  for (int mt = 0; mt < 4; mt++)
    #pragma unroll
    for (int j = 0; j < 2; j++) accO[mt][j] = zero4();
  float rs0 = 0.f, rs1 = 0.f;           // per-lane partial row sums (j=0,1)
  int nkt = 2 * qt + 2;
  uint4 ka0, ka1, va0, va1;
  ka0 = *(const uint4*)(kbase + (size_t)(sr)      * 64 + scc);
  ka1 = *(const uint4*)(kbase + (size_t)(sr + 32) * 64 + scc);
  va0 = *(const uint4*)(vbase + (size_t)(sr)      * 2048 + scc);
  va1 = *(const uint4*)(vbase + (size_t)(sr + 32) * 2048 + scc);
  *(uint4*)&Ks[sr * 72 + scc] = ka0; *(uint4*)&Ks[(sr + 32) * 72 + scc] = ka1;
  *(uint4*)&Vt[sr * 72 + scc] = va0; *(uint4*)&Vt[(sr + 32) * 72 + scc] = va1;
  __syncthreads();
  for (int kt = 0; kt < nkt; kt++){
    if (kt + 1 < nkt){                  // register-prefetch next K/V tile (T14: issue early)
      int kb2 = (kt + 1) * 64;
      ka0 = *(const uint4*)(kbase + (size_t)(kb2 + sr)      * 64 + scc);
      ka1 = *(const uint4*)(kbase + (size_t)(kb2 + sr + 32) * 64 + scc);
      va0 = *(const uint4*)(vbase + (size_t)(sr)      * 2048 + kb2 + scc);
      va1 = *(const uint4*)(vbase + (size_t)(sr + 32) * 2048 + kb2 + scc);
    }
    int ks0 = kt * 64;                  // tile's absolute k start
    if (ks0 <= q0 + 31){                // wave-uniform activity
      // ---- QK^T: S^T[64k][32q], per 16-k block
      #pragma unroll
      for (int kb = 0; kb < 4; kb++){
        s16x8 ak0 = *(const s16x8*)&Ks[(kb*16 + l16) * 72 + g*8];
        s16x8 ak1 = *(const s16x8*)&Ks[(kb*16 + l16) * 72 + 32 + g*8];
        #pragma unroll
        for (int j = 0; j < 2; j++){
          f32x4 s = zero4();
          s = MFMA(ak0, bq[j][0], s);
          s = MFMA(ak1, bq[j][1], s);
          if (ks0 + kb*16 + 15 > q0 + j*16){  // diagonal straddle: causal mask
            int qrow = q0 + j*16 + l16;
            #pragma unroll
            for (int r = 0; r < 4; r++)
              if (ks0 + kb*16 + g*4 + r > qrow) s[r] = -1e30f;
          }
          float p0 = fexp2(s[0]), p1 = fexp2(s[1]), p2 = fexp2(s[2]), p3 = fexp2(s[3]);
          if (j == 0) rs0 += (p0 + p1) + (p2 + p3);
          else        rs1 += (p0 + p1) + (p2 + p3);
          *(uint2*)&PsW[(j*16 + l16) * 72 + kb*16 + g*4] = make_uint2(pkbf(p0, p1), pkbf(p2, p3));
        }
      }
      // ---- PV: O^T[dh][q] += V^T[dh][k] * P^T[k][q], k = 64
      s16x8 av[4][2];
      #pragma unroll
      for (int mt = 0; mt < 4; mt++)
        #pragma unroll
        for (int kc = 0; kc < 2; kc++)
          av[mt][kc] = *(const s16x8*)&Vt[(mt*16 + l16) * 72 + kc*32 + g*8];
      #pragma unroll
      for (int j = 0; j < 2; j++){
        s16x8 bp0 = *(const s16x8*)&PsW[(j*16 + l16) * 72 + g*8];
        s16x8 bp1 = *(const s16x8*)&PsW[(j*16 + l16) * 72 + 32 + g*8];
        #pragma unroll
        for (int mt = 0; mt < 4; mt++){
          accO[mt][j] = MFMA(av[mt][0], bp0, accO[mt][j]);
          accO[mt][j] = MFMA(av[mt][1], bp1, accO[mt][j]);
        }
      }
    }
    if (kt + 1 < nkt){
      __syncthreads();
      *(uint4*)&Ks[sr * 72 + scc] = ka0; *(uint4*)&Ks[(sr + 32) * 72 + scc] = ka1;
      *(uint4*)&Vt[sr * 72 + scc] = va0; *(uint4*)&Vt[(sr + 32) * 72 + scc] = va1;
      __syncthreads();
    }
  }
  // per-wave normalize + store (no cross-wave merge needed)
  float rinv[2];
  #pragma unroll
  for (int j = 0; j < 2; j++){
    float l = (j == 0) ? rs0 : rs1;
    l += __shfl_xor(l, 16);
    l += __shfl_xor(l, 32);
    rinv[j] = 1.0f / l;
  }
  #pragma unroll
  for (int mt = 0; mt < 4; mt++)
    #pragma unroll
    for (int j = 0; j < 2; j++){
      float o0 = accO[mt][j][0] * rinv[j];
      float o1 = accO[mt][j][1] * rinv[j];
      float o2 = accO[mt][j][2] * rinv[j];
      float o3 = accO[mt][j][3] * rinv[j];
      *(uint2*)&O[((size_t)b * 2048 + q0 + j*16 + l16) * 1024 + h*64 + mt*16 + g*4] =
          make_uint2(pkbf(o0, o1), pkbf(o2, o3));
    }
}

// ---------------- output projection with split-K=4: [8192,1024] @ Wo^T + bo -> fp32 (atomicAdd)
__global__ __launch_bounds__(256) void k_oproj(const u16* __restrict__ Ob, const u16* __restrict__ wot,
    const float* __restrict__ bo, float* __restrict__ out){
  __shared__ u16 As[64][72];
  __shared__ u16 Bs[64][72];
  int rb = blockIdx.x, kc = blockIdx.y;
  int tid = threadIdx.x, wave = tid >> 6, lane = tid & 63;
  int l16 = lane & 15, g = lane >> 4;
  int wr = (wave & 1) * 32, wc = (wave >> 1) * 32;
  int row0 = rb * 64;
  f32x4 acc[2][2];
  acc[0][0]=zero4(); acc[0][1]=zero4(); acc[1][0]=zero4(); acc[1][1]=zero4();
  int r0s = tid >> 3, cc0 = (tid & 7) * 8, r1s = r0s + 32;
  for (int k0 = kc * 256; k0 < kc * 256 + 256; k0 += 64){
    __syncthreads();
    *(uint4*)&As[r0s][cc0] = *(const uint4*)(Ob + (size_t)(row0 + r0s) * 1024 + k0 + cc0);
    *(uint4*)&As[r1s][cc0] = *(const uint4*)(Ob + (size_t)(row0 + r1s) * 1024 + k0 + cc0);
    *(uint4*)&Bs[r0s][cc0] = *(const uint4*)(wot + (size_t)r0s * 1024 + k0 + cc0);
    *(uint4*)&Bs[r1s][cc0] = *(const uint4*)(wot + (size_t)r1s * 1024 + k0 + cc0);
    __syncthreads();
    #pragma unroll
    for (int c = 0; c < 2; c++){
      int kcc = c * 32;
      s16x8 a0 = *(const s16x8*)&As[wr      + l16][kcc + g * 8];
      s16x8 a1 = *(const s16x8*)&As[wr + 16 + l16][kcc + g * 8];
      s16x8 b0 = *(const s16x8*)&Bs[wc      + l16][kcc + g * 8];
      s16x8 b1 = *(const s16x8*)&Bs[wc + 16 + l16][kcc + g * 8];
      acc[0][0] = MFMA(a0, b0, acc[0][0]);
      acc[0][1] = MFMA(a0, b1, acc[0][1]);
      acc[1][0] = MFMA(a1, b0, acc[1][0]);
      acc[1][1] = MFMA(a1, b1, acc[1][1]);
    }
  }
  #pragma unroll
  for (int rt = 0; rt < 2; rt++){
    #pragma unroll
    for (int ct = 0; ct < 2; ct++){
      int col = wc + ct * 16 + l16;
      float bval = (kc == 0) ? bo[col] : 0.f;
      #pragma unroll
      for (int i = 0; i < 4; i++){
        int row = row0 + wr + rt * 16 + g * 4 + i;
        atomicAdd(&out[(size_t)row * 64 + col], acc[rt][ct][i] + bval);
      }
    }
  }
}

extern "C" void kernel_launch(void* const* d_in, const int* in_sizes, int n_in,
                              void* d_out, int out_size, void* d_ws, size_t ws_size,
                              hipStream_t stream){
  const float* x  = (const float*)d_in[0];
  const float* Wq = (const float*)d_in[1];
  const float* bq = (const float*)d_in[2];
  const float* Wk = (const float*)d_in[3];
  const float* bk = (const float*)d_in[4];
  const float* Wv = (const float*)d_in[5];
  const float* bv = (const float*)d_in[6];
  const float* Wo = (const float*)d_in[7];
  const float* bo = (const float*)d_in[8];

  u16* xb  = (u16*)d_ws;          // [8192][1024] bf16 x ; reused as attention output Ob
  u16* wt  = xb  + 8388608;       // [3][16][64][1024] transposed qkv weights
  u16* wot = wt  + 3145728;       // [64][1024] transposed Wo
  u16* Qb  = wot + 65536;         // [B][H][S][64] (pre-scaled by QSCALE)
  u16* Kb  = Qb  + 8388608;       // [B][H][S][64]
  u16* VTb = Kb  + 8388608;       // [B][H][64][S]
  u16* Ob  = xb;                  // alias: x dead after k_qkv
  float* out = (float*)d_out;

  hipMemsetAsync(d_out, 0, (size_t)out_size * sizeof(float), stream);
  k_cvt<<<8192, 256, 0, stream>>>(x, xb);
  k_twp<<<dim3(16, 49), 256, 0, stream>>>(Wq, Wk, Wv, Wo, wt, wot);
  k_qkv<<<dim3(64, 24), 256, 0, stream>>>(xb, wt, bq, bk, bv, Qb, Kb, VTb);
  k_attn<<<dim3(64, 16), 256, 0, stream>>>(Qb, Kb, VTb, Ob);
  k_oproj<<<dim3(128, 4), 256, 0, stream>>>(Ob, wot, bo, out);
}

// Round 5
// 227.753 us; speedup vs baseline: 1.0486x; 1.0194x over previous
//
#include <hip/hip_runtime.h>

typedef unsigned short u16;
typedef unsigned int u32;
typedef __attribute__((ext_vector_type(8))) short s16x8;
typedef __attribute__((ext_vector_type(4))) float f32x4;

#define MFMA(a,b,c) __builtin_amdgcn_mfma_f32_16x16x32_bf16((a),(b),(c),0,0,0)
#define QSCALE 0.18033688011112042f   // 0.125 * log2(e): folds attn scale + exp->exp2

// raw barrier + compiler memory fence (NO implicit vmcnt(0) drain, unlike __syncthreads)
#define BAR() do { asm volatile("" ::: "memory"); __builtin_amdgcn_s_barrier(); asm volatile("" ::: "memory"); } while(0)
#define WAITV(n) asm volatile("s_waitcnt vmcnt(" #n ")" ::: "memory")

__device__ __forceinline__ u16 bfc(float f){
  union { float f; unsigned int u; } c; c.f = f;
  return (u16)((c.u + 0x7fffu + ((c.u >> 16) & 1u)) >> 16);
}
// pack 2 f32 -> 2 bf16 (round-half-up) in one v_perm_b32
__device__ __forceinline__ u32 pkbf(float lo, float hi){
  union { float f; u32 u; } a, b; a.f = lo; b.f = hi;
  return __builtin_amdgcn_perm(b.u + 0x8000u, a.u + 0x8000u, 0x07060302u);
}
__device__ __forceinline__ float fexp2(float x){ return __builtin_amdgcn_exp2f(x); }
__device__ __forceinline__ f32x4 zero4(){ f32x4 z; z[0]=0.f; z[1]=0.f; z[2]=0.f; z[3]=0.f; return z; }

__device__ __forceinline__ void gload_lds16(const u16* g, u16* l){
  __builtin_amdgcn_global_load_lds((const __attribute__((address_space(1))) unsigned int*)g,
                                   (__attribute__((address_space(3))) unsigned int*)l, 16, 0, 0);
}

// ---------------- x fp32 -> bf16
__global__ __launch_bounds__(256) void k_cvt(const float* __restrict__ x, u16* __restrict__ xb){
  int i = (blockIdx.x * 256 + threadIdx.x) * 4;
  float4 v = *(const float4*)(x + i);
  *(uint2*)(xb + i) = make_uint2(pkbf(v.x, v.y), pkbf(v.z, v.w));
}

// ---------------- fused weight transpose+convert (Wq|Wk|Wv|Wo): [m][1024][64] f32 -> [m][64][1024] bf16
__global__ __launch_bounds__(256) void k_twp(const float* __restrict__ Wq, const float* __restrict__ Wk,
    const float* __restrict__ Wv, const float* __restrict__ Wo,
    u16* __restrict__ wt, u16* __restrict__ wot){
  __shared__ float t[64][65];
  int y = blockIdx.y, k0 = blockIdx.x * 64, tid = threadIdx.x;
  const float* src; u16* dst;
  if (y < 16)      { src = Wq + (size_t)y * 65536;        dst = wt + (size_t)y * 65536; }
  else if (y < 32) { src = Wk + (size_t)(y-16) * 65536;   dst = wt + (size_t)y * 65536; }
  else if (y < 48) { src = Wv + (size_t)(y-32) * 65536;   dst = wt + (size_t)y * 65536; }
  else             { src = Wo;                            dst = wot; }
  const float* s = src + (size_t)k0 * 64;
  int kl = tid >> 2, nc = (tid & 3) * 16;
  #pragma unroll
  for (int j = 0; j < 4; j++){
    float4 v = *(const float4*)(s + kl * 64 + nc + j * 4);
    t[kl][nc + j*4 + 0] = v.x; t[kl][nc + j*4 + 1] = v.y;
    t[kl][nc + j*4 + 2] = v.z; t[kl][nc + j*4 + 3] = v.w;
  }
  __syncthreads();
  int n = tid >> 2, kc = (tid & 3) * 16;
  u16 o[16];
  #pragma unroll
  for (int j = 0; j < 16; j++) o[j] = bfc(t[kc + j][n]);
  u16* d = dst + (size_t)n * 1024 + k0 + kc;
  *(uint4*)(d)     = *(uint4*)&o[0];
  *(uint4*)(d + 8) = *(uint4*)&o[8];
}

// ---------------- fused QKV projection (r5): GEMM M=8192, N=3072, K=1024; 128x128 tile.
// r4 + DEPTH: 3-slot LDS ring (48KB -> still 3 blocks/CU) with counted vmcnt that
// never drains in the main loop. Per K-step (BK=32):
//   WAITV(4)   -- slice s landed (issued 2 iters ago, ~2 iters of latency cover);
//                 slice s+1's 4 loads stay in flight
//   BAR        -- chip-wide: every wave did its own WAITV(4) first
//   stage(s+2) -- into slot (s+2)%3 == (s-1)%3, whose readers finished in iter s-1
//                 before they reached this barrier (WAR-safe, issue is post-barrier)
//   ds_read(s) + 16 MFMA (setprio-wrapped)
// In-flight loads at compute time target slot (s+2)%3 != s%3 -> no read overlap.
// r4 lesson: vmcnt(0) at step end = full drain of same-iter loads (80-230cyc cover
// vs 200-900cyc latency) -> pipeline was fake. T4: the gain of pipelining IS the
// counted vmcnt. Swizzle unchanged: phys_chunk = g ^ ((row>>1)&3), 2-way (free);
// stage source pre-swizzled with the same involution; ds_read offsets precomputed.
__global__ __launch_bounds__(256) void k_qkv(const u16* __restrict__ xb, const u16* __restrict__ wt,
    const float* __restrict__ bq, const float* __restrict__ bk, const float* __restrict__ bv,
    u16* __restrict__ Qo, u16* __restrict__ Ko, u16* __restrict__ VT){
  __shared__ u16 lds[24576];            // 48 KB: 3 slots x (A[4096] | B[4096]) u16
  int tid = threadIdx.x, w = tid >> 6, lane = tid & 63;
  int l16 = lane & 15, g = lane >> 4;
  int row0 = blockIdx.x * 128, col0 = blockIdx.y * 128;
  int wm = (w & 1) * 64, wn = (w >> 1) * 64;
  f32x4 acc[4][4];
  #pragma unroll
  for (int mt = 0; mt < 4; mt++)
    #pragma unroll
    for (int nt = 0; nt < 4; nt++) acc[mt][nt] = zero4();

  // stage sources: thread t fills phys 16B chunk t of each 8KB half; phys chunk
  // (row = gi*64 + t>>2, pc = t&3) holds logical chunk lc = pc ^ ((row>>1)&3).
  int trow = tid >> 2;
  int lc = (tid & 3) ^ ((tid >> 3) & 3);
  const u16* gpa = xb + (size_t)(row0 + trow) * 1024 + lc * 8;
  const u16* gpb = wt + (size_t)(col0 + trow) * 1024 + lc * 8;

  // loop-invariant swizzled ds_read offsets (u16 units; row stride 32, slot-relative)
  int afo[4], bfo[4];
  #pragma unroll
  for (int mt = 0; mt < 4; mt++){
    int r = wm + mt * 16 + l16;
    afo[mt] = r * 32 + ((g ^ ((r >> 1) & 3)) * 8);
  }
  #pragma unroll
  for (int nt = 0; nt < 4; nt++){
    int r = wn + nt * 16 + l16;
    bfo[nt] = 4096 + r * 32 + ((g ^ ((r >> 1) & 3)) * 8);
  }

  // stage slice sl into slot: 4 gloads/wave (A rows 0-63, 64-127, B rows 0-63, 64-127)
  auto stage = [&](int sl, int slot){
    u16* base = &lds[slot * 8192 + w * 512];
    int ko = sl * 32;
    gload_lds16(gpa + ko,             base);
    gload_lds16(gpa + ko + 64 * 1024, base + 2048);
    gload_lds16(gpb + ko,             base + 4096);
    gload_lds16(gpb + ko + 64 * 1024, base + 4096 + 2048);
  };
  auto compute = [&](int sel){
    s16x8 af[4], bf[4];
    #pragma unroll
    for (int mt = 0; mt < 4; mt++) af[mt] = *(const s16x8*)&lds[sel + afo[mt]];
    #pragma unroll
    for (int nt = 0; nt < 4; nt++) bf[nt] = *(const s16x8*)&lds[sel + bfo[nt]];
    __builtin_amdgcn_s_setprio(1);
    #pragma unroll
    for (int mt = 0; mt < 4; mt++)
      #pragma unroll
      for (int nt = 0; nt < 4; nt++) acc[mt][nt] = MFMA(af[mt], bf[nt], acc[mt][nt]);
    __builtin_amdgcn_s_setprio(0);
  };

  // prologue: 2 slices in flight
  stage(0, 0); stage(1, 1);
  #pragma unroll 3
  for (int s = 0; s < 30; ++s){
    WAITV(4);
    BAR();
    stage(s + 2, (s + 2) % 3);
    compute((s % 3) * 8192);
  }
  // tail: slices 30 (slot 0) and 31 (slot 1); no writers after
  WAITV(0); BAR();
  compute(0);
  compute(8192);

  // ---- epilogue (identical math to r2/r4)
  #pragma unroll
  for (int nt = 0; nt < 4; nt++){
    int n = col0 + wn + nt * 16 + l16;
    int wi = n >> 10, hh = (n >> 6) & 15, dh = n & 63;
    const float* bptr = (wi == 0) ? bq : (wi == 1) ? bk : bv;
    float bval = bptr[hh * 64 + dh];
    #pragma unroll
    for (int mt = 0; mt < 4; mt++){
      int m0 = row0 + wm + mt * 16 + g * 4;
      int bb = m0 >> 11, ss = m0 & 2047;
      if (wi == 2){
        u32 p0 = pkbf(acc[mt][nt][0] + bval, acc[mt][nt][1] + bval);
        u32 p1 = pkbf(acc[mt][nt][2] + bval, acc[mt][nt][3] + bval);
        *(uint2*)&VT[(((size_t)bb * 16 + hh) * 64 + dh) * 2048 + ss] = make_uint2(p0, p1);
      } else {
        u16* dst = (wi == 0) ? Qo : Ko;
        float scl = (wi == 0) ? QSCALE : 1.0f;
        #pragma unroll
        for (int i = 0; i < 4; i++)
          dst[(((size_t)bb * 16 + hh) * 2048 + ss + i) * 64 + dh] = bfc((acc[mt][nt][i] + bval) * scl);
      }
    }
  }
}

// ---------------- flash attention, S^T + FIXED-MAX softmax.
// wave = 32 q-rows x FULL k-range; 3 blocks/CU under launch_bounds(256,3), no spill.
__global__ __launch_bounds__(256, 3) void k_attn(const u16* __restrict__ Q, const u16* __restrict__ Kg,
    const u16* __restrict__ VT, u16* __restrict__ O){
  __shared__ u16 smem[18432];           // 36864B: Ks[64][72] | Vt[64][72] | Ps[4][32][72]
  u16* Ks = smem;                       // [kpos][dh], stride 72
  u16* Vt = smem + 4608;                // [dh][kpos], stride 72
  u16* Ps = smem + 9216;                // per-wave [32 q][72] (64 k + pad)
  int hbi = blockIdx.x;
  int qt = 15 - (int)blockIdx.y;        // long blocks (qt=15, 32 kt-iters) first
  int b = hbi >> 4, h = hbi & 15;
  int tid = threadIdx.x, wave = tid >> 6, lane = tid & 63;
  int l16 = lane & 15, g = lane >> 4;
  size_t hb = (size_t)hbi * 2048 * 64;
  const u16* kbase = Kg + hb;
  const u16* vbase = VT + hb;           // [64][2048]
  int sr = tid >> 3, scc = (tid & 7) * 8;
  u16* PsW = Ps + wave * (32 * 72);
  int q0 = qt * 128 + wave * 32;        // wave's 32 q-rows
  s16x8 bq[2][2];
  #pragma unroll
  for (int j = 0; j < 2; j++)
    #pragma unroll
    for (int c = 0; c < 2; c++)
      bq[j][c] = *(const s16x8*)(Q + hb + (size_t)(q0 + j*16 + l16) * 64 + c*32 + g*8);
  f32x4 accO[4][2];                     // [mt(dh)][j(q)]
  #pragma unroll
  for (int mt = 0; mt < 4; mt++)
    #pragma unroll
    for (int j = 0; j < 2; j++) accO[mt][j] = zero4();
  float rs0 = 0.f, rs1 = 0.f;           // per-lane partial row sums (j=0,1)
  int nkt = 2 * qt + 2;
  uint4 ka0, ka1, va0, va1;
  ka0 = *(const uint4*)(kbase + (size_t)(sr)      * 64 + scc);
  ka1 = *(const uint4*)(kbase + (size_t)(sr + 32) * 64 + scc);
  va0 = *(const uint4*)(vbase + (size_t)(sr)      * 2048 + scc);
  va1 = *(const uint4*)(vbase + (size_t)(sr + 32) * 2048 + scc);
  *(uint4*)&Ks[sr * 72 + scc] = ka0; *(uint4*)&Ks[(sr + 32) * 72 + scc] = ka1;
  *(uint4*)&Vt[sr * 72 + scc] = va0; *(uint4*)&Vt[(sr + 32) * 72 + scc] = va1;
  __syncthreads();
  for (int kt = 0; kt < nkt; kt++){
    if (kt + 1 < nkt){                  // register-prefetch next K/V tile (T14: issue early)
      int kb2 = (kt + 1) * 64;
      ka0 = *(const uint4*)(kbase + (size_t)(kb2 + sr)      * 64 + scc);
      ka1 = *(const uint4*)(kbase + (size_t)(kb2 + sr + 32) * 64 + scc);
      va0 = *(const uint4*)(vbase + (size_t)(sr)      * 2048 + kb2 + scc);
      va1 = *(const uint4*)(vbase + (size_t)(sr + 32) * 2048 + kb2 + scc);
    }
    int ks0 = kt * 64;                  // tile's absolute k start
    if (ks0 <= q0 + 31){                // wave-uniform activity
      // ---- QK^T: S^T[64k][32q], per 16-k block
      #pragma unroll
      for (int kb = 0; kb < 4; kb++){
        s16x8 ak0 = *(const s16x8*)&Ks[(kb*16 + l16) * 72 + g*8];
        s16x8 ak1 = *(const s16x8*)&Ks[(kb*16 + l16) * 72 + 32 + g*8];
        #pragma unroll
        for (int j = 0; j < 2; j++){
          f32x4 s = zero4();
          s = MFMA(ak0, bq[j][0], s);
          s = MFMA(ak1, bq[j][1], s);
          if (ks0 + kb*16 + 15 > q0 + j*16){  // diagonal straddle: causal mask
            int qrow = q0 + j*16 + l16;
            #pragma unroll
            for (int r = 0; r < 4; r++)
              if (ks0 + kb*16 + g*4 + r > qrow) s[r] = -1e30f;
          }
          float p0 = fexp2(s[0]), p1 = fexp2(s[1]), p2 = fexp2(s[2]), p3 = fexp2(s[3]);
          if (j == 0) rs0 += (p0 + p1) + (p2 + p3);
          else        rs1 += (p0 + p1) + (p2 + p3);
          *(uint2*)&PsW[(j*16 + l16) * 72 + kb*16 + g*4] = make_uint2(pkbf(p0, p1), pkbf(p2, p3));
        }
      }
      // ---- PV: O^T[dh][q] += V^T[dh][k] * P^T[k][q], k = 64
      s16x8 av[4][2];
      #pragma unroll
      for (int mt = 0; mt < 4; mt++)
        #pragma unroll
        for (int kc = 0; kc < 2; kc++)
          av[mt][kc] = *(const s16x8*)&Vt[(mt*16 + l16) * 72 + kc*32 + g*8];
      #pragma unroll
      for (int j = 0; j < 2; j++){
        s16x8 bp0 = *(const s16x8*)&PsW[(j*16 + l16) * 72 + g*8];
        s16x8 bp1 = *(const s16x8*)&PsW[(j*16 + l16) * 72 + 32 + g*8];
        #pragma unroll
        for (int mt = 0; mt < 4; mt++){
          accO[mt][j] = MFMA(av[mt][0], bp0, accO[mt][j]);
          accO[mt][j] = MFMA(av[mt][1], bp1, accO[mt][j]);
        }
      }
    }
    if (kt + 1 < nkt){
      __syncthreads();
      *(uint4*)&Ks[sr * 72 + scc] = ka0; *(uint4*)&Ks[(sr + 32) * 72 + scc] = ka1;
      *(uint4*)&Vt[sr * 72 + scc] = va0; *(uint4*)&Vt[(sr + 32) * 72 + scc] = va1;
      __syncthreads();
    }
  }
  // per-wave normalize + store (no cross-wave merge needed)
  float rinv[2];
  #pragma unroll
  for (int j = 0; j < 2; j++){
    float l = (j == 0) ? rs0 : rs1;
    l += __shfl_xor(l, 16);
    l += __shfl_xor(l, 32);
    rinv[j] = 1.0f / l;
  }
  #pragma unroll
  for (int mt = 0; mt < 4; mt++)
    #pragma unroll
    for (int j = 0; j < 2; j++){
      float o0 = accO[mt][j][0] * rinv[j];
      float o1 = accO[mt][j][1] * rinv[j];
      float o2 = accO[mt][j][2] * rinv[j];
      float o3 = accO[mt][j][3] * rinv[j];
      *(uint2*)&O[((size_t)b * 2048 + q0 + j*16 + l16) * 1024 + h*64 + mt*16 + g*4] =
          make_uint2(pkbf(o0, o1), pkbf(o2, o3));
    }
}

// ---------------- output projection with split-K=4: [8192,1024] @ Wo^T + bo -> fp32 (atomicAdd)
__global__ __launch_bounds__(256) void k_oproj(const u16* __restrict__ Ob, const u16* __restrict__ wot,
    const float* __restrict__ bo, float* __restrict__ out){
  __shared__ u16 As[64][72];
  __shared__ u16 Bs[64][72];
  int rb = blockIdx.x, kc = blockIdx.y;
  int tid = threadIdx.x, wave = tid >> 6, lane = tid & 63;
  int l16 = lane & 15, g = lane >> 4;
  int wr = (wave & 1) * 32, wc = (wave >> 1) * 32;
  int row0 = rb * 64;
  f32x4 acc[2][2];
  acc[0][0]=zero4(); acc[0][1]=zero4(); acc[1][0]=zero4(); acc[1][1]=zero4();
  int r0s = tid >> 3, cc0 = (tid & 7) * 8, r1s = r0s + 32;
  for (int k0 = kc * 256; k0 < kc * 256 + 256; k0 += 64){
    __syncthreads();
    *(uint4*)&As[r0s][cc0] = *(const uint4*)(Ob + (size_t)(row0 + r0s) * 1024 + k0 + cc0);
    *(uint4*)&As[r1s][cc0] = *(const uint4*)(Ob + (size_t)(row0 + r1s) * 1024 + k0 + cc0);
    *(uint4*)&Bs[r0s][cc0] = *(const uint4*)(wot + (size_t)r0s * 1024 + k0 + cc0);
    *(uint4*)&Bs[r1s][cc0] = *(const uint4*)(wot + (size_t)r1s * 1024 + k0 + cc0);
    __syncthreads();
    #pragma unroll
    for (int c = 0; c < 2; c++){
      int kcc = c * 32;
      s16x8 a0 = *(const s16x8*)&As[wr      + l16][kcc + g * 8];
      s16x8 a1 = *(const s16x8*)&As[wr + 16 + l16][kcc + g * 8];
      s16x8 b0 = *(const s16x8*)&Bs[wc      + l16][kcc + g * 8];
      s16x8 b1 = *(const s16x8*)&Bs[wc + 16 + l16][kcc + g * 8];
      acc[0][0] = MFMA(a0, b0, acc[0][0]);
      acc[0][1] = MFMA(a0, b1, acc[0][1]);
      acc[1][0] = MFMA(a1, b0, acc[1][0]);
      acc[1][1] = MFMA(a1, b1, acc[1][1]);
    }
  }
  #pragma unroll
  for (int rt = 0; rt < 2; rt++){
    #pragma unroll
    for (int ct = 0; ct < 2; ct++){
      int col = wc + ct * 16 + l16;
      float bval = (kc == 0) ? bo[col] : 0.f;
      #pragma unroll
      for (int i = 0; i < 4; i++){
        int row = row0 + wr + rt * 16 + g * 4 + i;
        atomicAdd(&out[(size_t)row * 64 + col], acc[rt][ct][i] + bval);
      }
    }
  }
}

extern "C" void kernel_launch(void* const* d_in, const int* in_sizes, int n_in,
                              void* d_out, int out_size, void* d_ws, size_t ws_size,
                              hipStream_t stream){
  const float* x  = (const float*)d_in[0];
  const float* Wq = (const float*)d_in[1];
  const float* bq = (const float*)d_in[2];
  const float* Wk = (const float*)d_in[3];
  const float* bk = (const float*)d_in[4];
  const float* Wv = (const float*)d_in[5];
  const float* bv = (const float*)d_in[6];
  const float* Wo = (const float*)d_in[7];
  const float* bo = (const float*)d_in[8];

  u16* xb  = (u16*)d_ws;          // [8192][1024] bf16 x ; reused as attention output Ob
  u16* wt  = xb  + 8388608;       // [3][16][64][1024] transposed qkv weights
  u16* wot = wt  + 3145728;       // [64][1024] transposed Wo
  u16* Qb  = wot + 65536;         // [B][H][S][64] (pre-scaled by QSCALE)
  u16* Kb  = Qb  + 8388608;       // [B][H][S][64]
  u16* VTb = Kb  + 8388608;       // [B][H][64][S]
  u16* Ob  = xb;                  // alias: x dead after k_qkv
  float* out = (float*)d_out;

  hipMemsetAsync(d_out, 0, (size_t)out_size * sizeof(float), stream);
  k_cvt<<<8192, 256, 0, stream>>>(x, xb);
  k_twp<<<dim3(16, 49), 256, 0, stream>>>(Wq, Wk, Wv, Wo, wt, wot);
  k_qkv<<<dim3(64, 24), 256, 0, stream>>>(xb, wt, bq, bk, bv, Qb, Kb, VTb);
  k_attn<<<dim3(64, 16), 256, 0, stream>>>(Qb, Kb, VTb, Ob);
  k_oproj<<<dim3(128, 4), 256, 0, stream>>>(Ob, wot, bo, out);
}